// Round 2
// baseline (337.581 us; speedup 1.0000x reference)
//
#include <hip/hip_runtime.h>
#include <math.h>

// VectorQuantizer, MFMA filter + exact-fp32 rescore.  N=32768 rows x K=8192
// codes, dim 64.
//
// R7 = R6 algorithm + R5 staging + explicit software pipeline.
//   R6 post-mortem: single-sweep restructure was right (MFMA work = 18/32 of
//   R5, MfmaUtil ratio confirms) but global_load_lds staging quadrupled
//   per-phase cost (8.7k -> 34k cyc): the DMA can't be hoisted above the
//   barrier, so every phase exposed full L2 latency behind vmcnt(0)+barrier,
//   and the permuted-lane source degraded coalescing.  All pipes idle
//   (MfmaUtil 6, VALU 20, HBM 1%).
//   R7: revert staging to global->VGPR -> swizzled ds_write_b128 (R5's, whose
//   phases measured 8.7k cyc), and make the overlap explicit (T14 split):
//   LOADREGS(ch+1) issues right after the post-write barrier so the loads
//   retire under chunk ch's MFMA/emit compute; WRITEREGS lands next phase.
//
// Algorithm (verified absmax 0 in R6):
//   seed phase = chunks 0..1 (256 codes): per-row max of S~ via MFMA,
//   butterfly-reduced in-register -> thr = seed_max - HALF_DELTA (VGPRs).
//   Then ONE emission sweep over all 16 chunks: S~ >= thr -> candidate.
//   Correctness: rescore is exact, so any thr <= S~(k_true) gives a superset;
//   S~(k*) >= S~max_Q - HALF_DELTA >= seed_max - HALF_DELTA = thr.
//   ~10 cands/row/quarter expected -> ~1300/block, CAND_CAP 3072.
// Exact pipeline unchanged: S = sequential __fmaf_rn chain c=0..63;
// normx = numpy pairwise(n=64); d = fl(normx - 2S); (d_bits<<13|k) u64
// atomicMin = value-then-lowest-index; 4 k-quarters merge in vq_out.

#define DIM      64
#define NCODE    8192
#define NROWS    32768
#define RPB      128               // rows per block: 4 waves x 2 row-tiles x 16
#define KQ       2048              // codes per block (gridDim.y = 4)
#define CHUNK    128               // codes staged in LDS at a time (16 KB)
#define NCHUNK   (KQ / CHUNK)      // 16
#define SEED_CH  2                 // seed chunks (256 codes) for the threshold
#define HALF_DELTA 4.0e-5f
#define CAND_CAP 3072

typedef __attribute__((ext_vector_type(8))) short frag8;   // 8 bf16
typedef __attribute__((ext_vector_type(4))) float f32x4;

__device__ __forceinline__ unsigned short f2bf_rne(float f) {
  unsigned u = __float_as_uint(f);
  return (unsigned short)((u + 0x7FFFu + ((u >> 16) & 1u)) >> 16);
}

// ---- kernel 0: codebook fp32 -> bf16 (RNE), 8192x64 = 1 MB in ws ----
__global__ __launch_bounds__(256) void cvt_emb(const float* __restrict__ emb,
                                               unsigned short* __restrict__ ebf) {
  const int i = (blockIdx.x * 256 + threadIdx.x) * 8;
  const float4 a = *(const float4*)(emb + i);
  const float4 c = *(const float4*)(emb + i + 4);
  union { unsigned short u[8]; uint4 v; } o;
  o.u[0] = f2bf_rne(a.x); o.u[1] = f2bf_rne(a.y);
  o.u[2] = f2bf_rne(a.z); o.u[3] = f2bf_rne(a.w);
  o.u[4] = f2bf_rne(c.x); o.u[5] = f2bf_rne(c.y);
  o.u[6] = f2bf_rne(c.z); o.u[7] = f2bf_rne(c.w);
  *(uint4*)(ebf + i) = o.v;
}

// ---- kernel 1: per (128-row group, 2048-code quarter) ----
__global__ __launch_bounds__(256) void vq_main(
    const float* __restrict__ x, const float* __restrict__ emb,
    const unsigned short* __restrict__ ebf,
    unsigned long long* __restrict__ wsbest)
{
  __shared__ uint4 ldsB[CHUNK * 8];            // 16 KB bf16 codes (16B units)
  __shared__ float s_normx[RPB];
  __shared__ unsigned long long s_best[RPB];
  __shared__ unsigned s_cand[CAND_CAP];        // (row_l<<11 | k_local)
  __shared__ int s_cnt;

  const int tid  = threadIdx.x;
  const int lane = tid & 63;
  const int wave = tid >> 6;
  const int s    = lane & 15;                  // MFMA m / n index
  const int q    = lane >> 4;                  // MFMA quad
  const int rowbase = blockIdx.x * RPB;
  const int kbase   = blockIdx.y * KQ;
  const int b    = rowbase >> 10;
  const int hw0  = rowbase & 1023;             // <= 896, block stays in one b
  const float* xb = x + (size_t)b * (DIM * 1024);

  if (tid == 0) s_cnt = 0;

  // normx for row rowbase+tid (tid<128) — numpy pairwise_sum(n=64), bit-exact
  if (tid < RPB) {
    s_best[tid] = ~0ull;
    float p[DIM];
#pragma unroll
    for (int c = 0; c < DIM; ++c) {
      const float v = xb[(size_t)c * 1024 + hw0 + tid];
      p[c] = __fmul_rn(v, v);
    }
    float r8[8];
#pragma unroll
    for (int j = 0; j < 8; ++j) {
      float ss = p[j];
#pragma unroll
      for (int m = 1; m < 8; ++m) ss = __fadd_rn(ss, p[m * 8 + j]);
      r8[j] = ss;
    }
    const float t0 = __fadd_rn(r8[0], r8[1]), t1 = __fadd_rn(r8[2], r8[3]);
    const float t2 = __fadd_rn(r8[4], r8[5]), t3 = __fadd_rn(r8[6], r8[7]);
    s_normx[tid] = __fadd_rn(__fadd_rn(t0, t1), __fadd_rn(t2, t3));
  }

  // A-frags: wave owns 32 rows = 2 row-tiles of 16.  A[m=s][k=q*8+j].
  frag8 afr[2][2];
#pragma unroll
  for (int rt = 0; rt < 2; ++rt) {
    const float* xp = xb + hw0 + wave * 32 + rt * 16 + s;
#pragma unroll
    for (int h = 0; h < 2; ++h) {
      frag8 f;
#pragma unroll
      for (int j = 0; j < 8; ++j)
        f[j] = (short)f2bf_rne(xp[(size_t)(h * 32 + q * 8 + j) * 1024]);
      afr[rt][h] = f;
    }
  }

  // LDS B layout: slot code*8 + (j ^ (code&7)) holds 16B chunk j of code.
  // Staged global->VGPR (LOADREGS, 2 threads/code, 64B each) then swizzled
  // ds_write_b128 (WRITEREGS).  Frag read (code = t*16+s): lbA -> chunk q
  // (c 0..31), lbB -> chunk 4+q.
  const int lbA = s * 8 + ((q)     ^ (s & 7));
  const int lbB = s * 8 + ((4 + q) ^ (s & 7));
  const frag8* ldsF = (const frag8*)ldsB;

  const int st_code = tid >> 1, st_half = tid & 1, st_sw = st_code & 7;
  uint4 st[4];

#define LOADREGS(ch_)                                                          \
  {                                                                            \
    const uint4* src = (const uint4*)(ebf +                                    \
        (size_t)(kbase + (ch_) * CHUNK + st_code) * DIM) + st_half * 4;        \
    st[0] = src[0]; st[1] = src[1]; st[2] = src[2]; st[3] = src[3];            \
  }

#define WRITEREGS()                                                            \
  {                                                                            \
    _Pragma("unroll")                                                          \
    for (int j = 0; j < 4; ++j)                                                \
      ldsB[st_code * 8 + ((st_half * 4 + j) ^ st_sw)] = st[j];                 \
  }

  const f32x4 z4 = {0.f, 0.f, 0.f, 0.f};

  // ---- seed phase: per-row max of S~ over chunks 0..SEED_CH-1 ----
  f32x4 smax[2];
  smax[0] = (f32x4){-1e30f, -1e30f, -1e30f, -1e30f};
  smax[1] = smax[0];

  LOADREGS(0);
#pragma unroll
  for (int ch = 0; ch < SEED_CH; ++ch) {
    __syncthreads();
    WRITEREGS();
    __syncthreads();
    // prefetch: seed ch+1, then chunk 0 again for the emission sweep
    if (ch + 1 < SEED_CH) { LOADREGS(ch + 1); } else { LOADREGS(0); }
#pragma unroll
    for (int t = 0; t < 8; ++t) {
      const frag8 b0 = ldsF[lbA + t * 128];
      const frag8 b1 = ldsF[lbB + t * 128];
#pragma unroll
      for (int rt = 0; rt < 2; ++rt) {
        f32x4 d = __builtin_amdgcn_mfma_f32_16x16x32_bf16(afr[rt][0], b0, z4, 0, 0, 0);
        d = __builtin_amdgcn_mfma_f32_16x16x32_bf16(afr[rt][1], b1, d, 0, 0, 0);
        smax[rt][0] = fmaxf(smax[rt][0], d[0]);
        smax[rt][1] = fmaxf(smax[rt][1], d[1]);
        smax[rt][2] = fmaxf(smax[rt][2], d[2]);
        smax[rt][3] = fmaxf(smax[rt][3], d[3]);
      }
    }
  }

  // butterfly over the 16 code-columns: every lane ends with its row's seed max
  float thr[2][4];
#pragma unroll
  for (int rt = 0; rt < 2; ++rt)
#pragma unroll
    for (int r = 0; r < 4; ++r) {
      float v = smax[rt][r];
      v = fmaxf(v, __shfl_xor(v, 1, 64));
      v = fmaxf(v, __shfl_xor(v, 2, 64));
      v = fmaxf(v, __shfl_xor(v, 4, 64));
      v = fmaxf(v, __shfl_xor(v, 8, 64));
      thr[rt][r] = v - HALF_DELTA;             // fixed threshold for the sweep
    }

  // ---- single emission sweep: S~ >= thr -> candidate ----
  for (int ch = 0; ch < NCHUNK; ++ch) {
    __syncthreads();
    WRITEREGS();
    __syncthreads();
    if (ch + 1 < NCHUNK) LOADREGS(ch + 1);     // hide next loads under compute
#pragma unroll
    for (int t = 0; t < 8; ++t) {
      const frag8 b0 = ldsF[lbA + t * 128];
      const frag8 b1 = ldsF[lbB + t * 128];
      const int kl = ch * CHUNK + t * 16 + s;
#pragma unroll
      for (int rt = 0; rt < 2; ++rt) {
        f32x4 d = __builtin_amdgcn_mfma_f32_16x16x32_bf16(afr[rt][0], b0, z4, 0, 0, 0);
        d = __builtin_amdgcn_mfma_f32_16x16x32_bf16(afr[rt][1], b1, d, 0, 0, 0);
        if ((d[0] >= thr[rt][0]) | (d[1] >= thr[rt][1]) |
            (d[2] >= thr[rt][2]) | (d[3] >= thr[rt][3])) {
#pragma unroll
          for (int r = 0; r < 4; ++r) {
            if (d[r] >= thr[rt][r]) {
              const int pos = atomicAdd(&s_cnt, 1);
              if (pos < CAND_CAP)
                s_cand[pos] = ((unsigned)(wave * 32 + rt * 16 + q * 4 + r) << 11) |
                              (unsigned)kl;
            }
          }
        }
      }
    }
  }
  __syncthreads();

  // ---- exact rescore of candidates (bit-exact numpy fp32 pipeline) ----
  const int cnt = min(s_cnt, CAND_CAP);
  for (int i = tid; i < cnt; i += 256) {
    const unsigned e = s_cand[i];
    const int row_l = (int)(e >> 11);
    const int kg = kbase + (int)(e & 0x7FFu);
    const float* ep = emb + (size_t)kg * DIM;
    const float* xp = xb + hw0 + row_l;
    float S = 0.f;
#pragma unroll
    for (int c = 0; c < DIM; ++c) S = __fmaf_rn(xp[(size_t)c * 1024], ep[c], S);
    const float dd = __fsub_rn(s_normx[row_l], __fadd_rn(S, S));
    const unsigned long long pack =
        ((unsigned long long)__float_as_uint(dd) << 13) | (unsigned long long)kg;
    atomicMin(&s_best[row_l], pack);
  }
  __syncthreads();

  if (tid < RPB)
    wsbest[(size_t)(rowbase + tid) * 4 + blockIdx.y] = s_best[tid];
}

// ---- kernel 2: merge quarters, write indices + gather z_q ----
__global__ __launch_bounds__(256) void vq_out(
    const float* __restrict__ emb, const unsigned long long* __restrict__ wsbest,
    float* __restrict__ zq, float* __restrict__ idx_out)
{
  const int row = blockIdx.x * 256 + threadIdx.x;
  unsigned long long p = wsbest[(size_t)row * 4];
#pragma unroll
  for (int j = 1; j < 4; ++j) {
    const unsigned long long pj = wsbest[(size_t)row * 4 + j];
    if (pj < p) p = pj;                        // d-major, then lowest k
  }
  const int k = (int)(p & 0x1FFFull);
  idx_out[row] = (float)k;
  const int b = row >> 10, hw = row & 1023;
  const float* ep = emb + (size_t)k * DIM;
  float* zp = zq + (size_t)b * (DIM * 1024) + hw;
#pragma unroll
  for (int c = 0; c < DIM; ++c) zp[(size_t)c * 1024] = ep[c];
}

extern "C" void kernel_launch(void* const* d_in, const int* in_sizes, int n_in,
                              void* d_out, int out_size, void* d_ws, size_t ws_size,
                              hipStream_t stream) {
  const float* x   = (const float*)d_in[0];   // [32, 64, 32, 32] fp32
  const float* emb = (const float*)d_in[1];   // [8192, 64] fp32

  float* zq      = (float*)d_out;
  float* idx_out = zq + (size_t)NROWS * DIM;

  unsigned short*     ebf    = (unsigned short*)d_ws;                          // 1 MB
  unsigned long long* wsbest = (unsigned long long*)((char*)d_ws + (1 << 20)); // 1 MB

  cvt_emb<<<dim3(256), 256, 0, stream>>>(emb, ebf);
  vq_main<<<dim3(NROWS / RPB, 4), 256, 0, stream>>>(x, emb, ebf, wsbest);
  vq_out<<<dim3(NROWS / 256), 256, 0, stream>>>(emb, wsbest, zq, idx_out);
}

// Round 3
// 300.224 us; speedup vs baseline: 1.1244x; 1.1244x over previous
//
#include <hip/hip_runtime.h>
#include <math.h>

// VectorQuantizer, MFMA filter + exact-fp32 rescore.  N=32768 rows x K=8192
// codes, dim 64.
//
// R8 = R5 verbatim with ONE change: sweep A truncated to SEED_CH=2 chunks.
//   R6/R7 post-mortem: the single-sweep idea was right, but the rewrites
//   added ~28 live VGPRs (st[] prefetch, vgpr-thr, z4) -> 60->88 VGPR ->
//   scratch spill in the hot loop (WRITE_SIZE 2->22 MB, VALU/phase doubled,
//   all pipes idle).  R8 reverts to R5's exact code (60 VGPR, no spill,
//   8.7k cyc/phase) and only shortens sweep A: per-row max over the first
//   256 codes instead of all 2048.  thr = seed_max - HALF_DELTA <= true
//   quarter max - HALF_DELTA, so sweep B still emits a guaranteed superset
//   of the exact argmin; the exact-fp32 rescore fixes the rest (semantics
//   already verified absmax 0 in R6/R7).  18 phases instead of 32.
//   Candidates/block grow ~140 -> ~900 (E beaters of max-of-256 ~ 7/row);
//   CAND_CAP 3072 (~13 sigma).  Grid stays 1024 blocks = 4/CU.
//
// Exact pipeline unchanged: S = sequential __fmaf_rn chain c=0..63;
// normx = numpy pairwise(n=64); d = fl(normx - 2S); (d_bits<<13|k) u64
// atomicMin = value-then-lowest-index; 4 k-quarters merge in vq_out.

#define DIM      64
#define NCODE    8192
#define NROWS    32768
#define RPB      128               // rows per block: 4 waves x 2 row-tiles x 16
#define KQ       2048              // codes per block (gridDim.y = 4)
#define CHUNK    128               // codes staged in LDS at a time (16 KB)
#define NCHUNK   (KQ / CHUNK)      // 16
#define SEED_CH  2                 // seed chunks (256 codes) for the threshold
#define HALF_DELTA 4.0e-5f
#define CAND_CAP 3072

typedef __attribute__((ext_vector_type(8))) short frag8;   // 8 bf16
typedef __attribute__((ext_vector_type(4))) float f32x4;

__device__ __forceinline__ unsigned short f2bf_rne(float f) {
  unsigned u = __float_as_uint(f);
  return (unsigned short)((u + 0x7FFFu + ((u >> 16) & 1u)) >> 16);
}

// ---- kernel 0: codebook fp32 -> bf16 (RNE), 8192x64 = 1 MB in ws ----
__global__ __launch_bounds__(256) void cvt_emb(const float* __restrict__ emb,
                                               unsigned short* __restrict__ ebf) {
  const int i = (blockIdx.x * 256 + threadIdx.x) * 8;
  const float4 a = *(const float4*)(emb + i);
  const float4 c = *(const float4*)(emb + i + 4);
  union { unsigned short u[8]; uint4 v; } o;
  o.u[0] = f2bf_rne(a.x); o.u[1] = f2bf_rne(a.y);
  o.u[2] = f2bf_rne(a.z); o.u[3] = f2bf_rne(a.w);
  o.u[4] = f2bf_rne(c.x); o.u[5] = f2bf_rne(c.y);
  o.u[6] = f2bf_rne(c.z); o.u[7] = f2bf_rne(c.w);
  *(uint4*)(ebf + i) = o.v;
}

// ---- kernel 1: per (128-row group, 2048-code quarter) ----
__global__ __launch_bounds__(256) void vq_main(
    const float* __restrict__ x, const float* __restrict__ emb,
    const unsigned short* __restrict__ ebf,
    unsigned long long* __restrict__ wsbest)
{
  __shared__ uint4 ldsB[CHUNK * 8];            // 16 KB bf16 codes (16B units)
  __shared__ float s_normx[RPB];
  __shared__ float s_mrow[RPB];
  __shared__ unsigned long long s_best[RPB];
  __shared__ unsigned s_cand[CAND_CAP];        // (row_l<<11 | k_local)
  __shared__ int s_cnt;

  const int tid  = threadIdx.x;
  const int lane = tid & 63;
  const int wave = tid >> 6;
  const int s    = lane & 15;                  // MFMA m / n index
  const int q    = lane >> 4;                  // MFMA quad
  const int rowbase = blockIdx.x * RPB;
  const int kbase   = blockIdx.y * KQ;
  const int b    = rowbase >> 10;
  const int hw0  = rowbase & 1023;             // <= 896, block stays in one b
  const float* xb = x + (size_t)b * (DIM * 1024);

  if (tid == 0) s_cnt = 0;

  // normx for row rowbase+tid (tid<128) — numpy pairwise_sum(n=64), bit-exact
  if (tid < RPB) {
    s_best[tid] = ~0ull;
    float p[DIM];
#pragma unroll
    for (int c = 0; c < DIM; ++c) {
      const float v = xb[(size_t)c * 1024 + hw0 + tid];
      p[c] = __fmul_rn(v, v);
    }
    float r8[8];
#pragma unroll
    for (int j = 0; j < 8; ++j) {
      float ss = p[j];
#pragma unroll
      for (int m = 1; m < 8; ++m) ss = __fadd_rn(ss, p[m * 8 + j]);
      r8[j] = ss;
    }
    const float t0 = __fadd_rn(r8[0], r8[1]), t1 = __fadd_rn(r8[2], r8[3]);
    const float t2 = __fadd_rn(r8[4], r8[5]), t3 = __fadd_rn(r8[6], r8[7]);
    s_normx[tid] = __fadd_rn(__fadd_rn(t0, t1), __fadd_rn(t2, t3));
  }

  // A-frags: wave owns 32 rows = 2 row-tiles of 16.  A[m=s][k=q*8+j].
  frag8 afr[2][2];
#pragma unroll
  for (int rt = 0; rt < 2; ++rt) {
    const float* xp = xb + hw0 + wave * 32 + rt * 16 + s;
#pragma unroll
    for (int h = 0; h < 2; ++h) {
      frag8 f;
#pragma unroll
      for (int j = 0; j < 8; ++j)
        f[j] = (short)f2bf_rne(xp[(size_t)(h * 32 + q * 8 + j) * 1024]);
      afr[rt][h] = f;
    }
  }

  // LDS B layout: slot code*8 + (j ^ (code&7)) holds 16B chunk j of code.
  // Frag read (code = t*16+s): lbA -> chunk q (c 0..31), lbB -> chunk 4+q.
  const int lbA = s * 8 + ((q)     ^ (s & 7));
  const int lbB = s * 8 + ((4 + q) ^ (s & 7));
  const frag8* ldsF = (const frag8*)ldsB;

  // ---- sweep A (seed): per-row max of S~ over the first SEED_CH chunks ----
  f32x4 smax[2];
#pragma unroll
  for (int rt = 0; rt < 2; ++rt) smax[rt] = (f32x4){-1e30f, -1e30f, -1e30f, -1e30f};

  for (int ch = 0; ch < SEED_CH; ++ch) {
    __syncthreads();
    {
      const int code = tid >> 1, half = tid & 1;   // 2 threads per code, 64B each
      const uint4* src = (const uint4*)(ebf + (size_t)(kbase + ch * CHUNK + code) * DIM) + half * 4;
      const int sw = code & 7;
#pragma unroll
      for (int j = 0; j < 4; ++j) ldsB[code * 8 + ((half * 4 + j) ^ sw)] = src[j];
    }
    __syncthreads();
#pragma unroll
    for (int t = 0; t < 8; ++t) {
      const frag8 b0 = ldsF[lbA + t * 128];
      const frag8 b1 = ldsF[lbB + t * 128];
#pragma unroll
      for (int rt = 0; rt < 2; ++rt) {
        f32x4 d = {0.f, 0.f, 0.f, 0.f};
        d = __builtin_amdgcn_mfma_f32_16x16x32_bf16(afr[rt][0], b0, d, 0, 0, 0);
        d = __builtin_amdgcn_mfma_f32_16x16x32_bf16(afr[rt][1], b1, d, 0, 0, 0);
        smax[rt][0] = fmaxf(smax[rt][0], d[0]);
        smax[rt][1] = fmaxf(smax[rt][1], d[1]);
        smax[rt][2] = fmaxf(smax[rt][2], d[2]);
        smax[rt][3] = fmaxf(smax[rt][3], d[3]);
      }
    }
  }

  // reduce over the 16 code-columns (lane&15); D row = q*4+r
#pragma unroll
  for (int rt = 0; rt < 2; ++rt)
#pragma unroll
    for (int r = 0; r < 4; ++r) {
      float v = smax[rt][r];
      v = fmaxf(v, __shfl_xor(v, 1, 64));
      v = fmaxf(v, __shfl_xor(v, 2, 64));
      v = fmaxf(v, __shfl_xor(v, 4, 64));
      v = fmaxf(v, __shfl_xor(v, 8, 64));
      if (s == 0) s_mrow[wave * 32 + rt * 16 + q * 4 + r] = v;
    }
  __syncthreads();

  float thr[2][4];
#pragma unroll
  for (int rt = 0; rt < 2; ++rt)
#pragma unroll
    for (int r = 0; r < 4; ++r)
      thr[rt][r] = s_mrow[wave * 32 + rt * 16 + q * 4 + r] - HALF_DELTA;

  // ---- sweep B: full quarter, emit candidates vs seed threshold ----
  for (int ch = 0; ch < NCHUNK; ++ch) {
    __syncthreads();
    {
      const int code = tid >> 1, half = tid & 1;
      const uint4* src = (const uint4*)(ebf + (size_t)(kbase + ch * CHUNK + code) * DIM) + half * 4;
      const int sw = code & 7;
#pragma unroll
      for (int j = 0; j < 4; ++j) ldsB[code * 8 + ((half * 4 + j) ^ sw)] = src[j];
    }
    __syncthreads();
#pragma unroll
    for (int t = 0; t < 8; ++t) {
      const frag8 b0 = ldsF[lbA + t * 128];
      const frag8 b1 = ldsF[lbB + t * 128];
      const int kl = ch * CHUNK + t * 16 + s;
#pragma unroll
      for (int rt = 0; rt < 2; ++rt) {
        f32x4 d = {0.f, 0.f, 0.f, 0.f};
        d = __builtin_amdgcn_mfma_f32_16x16x32_bf16(afr[rt][0], b0, d, 0, 0, 0);
        d = __builtin_amdgcn_mfma_f32_16x16x32_bf16(afr[rt][1], b1, d, 0, 0, 0);
#pragma unroll
        for (int r = 0; r < 4; ++r) {
          if (d[r] >= thr[rt][r]) {
            const int pos = atomicAdd(&s_cnt, 1);
            if (pos < CAND_CAP)
              s_cand[pos] = ((unsigned)(wave * 32 + rt * 16 + q * 4 + r) << 11) | (unsigned)kl;
          }
        }
      }
    }
  }
  __syncthreads();

  // ---- exact rescore of candidates (bit-exact numpy fp32 pipeline) ----
  const int cnt = min(s_cnt, CAND_CAP);
  for (int i = tid; i < cnt; i += 256) {
    const unsigned e = s_cand[i];
    const int row_l = (int)(e >> 11);
    const int kg = kbase + (int)(e & 0x7FFu);
    const float* ep = emb + (size_t)kg * DIM;
    const float* xp = xb + hw0 + row_l;
    float S = 0.f;
#pragma unroll
    for (int c = 0; c < DIM; ++c) S = __fmaf_rn(xp[(size_t)c * 1024], ep[c], S);
    const float dd = __fsub_rn(s_normx[row_l], __fadd_rn(S, S));
    const unsigned long long pack =
        ((unsigned long long)__float_as_uint(dd) << 13) | (unsigned long long)kg;
    atomicMin(&s_best[row_l], pack);
  }
  __syncthreads();

  if (tid < RPB)
    wsbest[(size_t)(rowbase + tid) * 4 + blockIdx.y] = s_best[tid];
}

// ---- kernel 2: merge quarters, write indices + gather z_q ----
__global__ __launch_bounds__(256) void vq_out(
    const float* __restrict__ emb, const unsigned long long* __restrict__ wsbest,
    float* __restrict__ zq, float* __restrict__ idx_out)
{
  const int row = blockIdx.x * 256 + threadIdx.x;
  unsigned long long p = wsbest[(size_t)row * 4];
#pragma unroll
  for (int j = 1; j < 4; ++j) {
    const unsigned long long pj = wsbest[(size_t)row * 4 + j];
    if (pj < p) p = pj;                        // d-major, then lowest k
  }
  const int k = (int)(p & 0x1FFFull);
  idx_out[row] = (float)k;
  const int b = row >> 10, hw = row & 1023;
  const float* ep = emb + (size_t)k * DIM;
  float* zp = zq + (size_t)b * (DIM * 1024) + hw;
#pragma unroll
  for (int c = 0; c < DIM; ++c) zp[(size_t)c * 1024] = ep[c];
}

extern "C" void kernel_launch(void* const* d_in, const int* in_sizes, int n_in,
                              void* d_out, int out_size, void* d_ws, size_t ws_size,
                              hipStream_t stream) {
  const float* x   = (const float*)d_in[0];   // [32, 64, 32, 32] fp32
  const float* emb = (const float*)d_in[1];   // [8192, 64] fp32

  float* zq      = (float*)d_out;
  float* idx_out = zq + (size_t)NROWS * DIM;

  unsigned short*     ebf    = (unsigned short*)d_ws;                          // 1 MB
  unsigned long long* wsbest = (unsigned long long*)((char*)d_ws + (1 << 20)); // 1 MB

  cvt_emb<<<dim3(256), 256, 0, stream>>>(emb, ebf);
  vq_main<<<dim3(NROWS / RPB, 4), 256, 0, stream>>>(x, emb, ebf, wsbest);
  vq_out<<<dim3(NROWS / 256), 256, 0, stream>>>(emb, wsbest, zq, idx_out);
}

// Round 4
// 291.657 us; speedup vs baseline: 1.1575x; 1.0294x over previous
//
#include <hip/hip_runtime.h>
#include <math.h>

// VectorQuantizer, MFMA filter + exact-fp32 rescore.  N=32768 rows x K=8192
// codes, dim 64.
//
// R9 = R8 + ONE change: the exact rescore reads xT[row][c] (row-major copy
// of x) instead of x[c][row].
//   R8 post-mortem: R6/R7/R8 (different staging, same wall time) proved the
//   stall was never staging.  Common factor: seed threshold -> ~8 cand/row
//   -> ~1M rescores, each reading 64 floats STRIDED 4KB = 64 cache lines
//   (4KB L2 traffic) per 256B of data.  Total ~4GB L2 traffic ~ 116us at the
//   34.5 TB/s L2 ceiling = the whole slowdown (also explains +1.3MB FETCH).
//   Fix: a 5us tiled-transpose kernel writes xT (8MB) into the zq OUTPUT
//   region (vq_out fully overwrites zq later and never reads it -> safe, no
//   workspace growth).  Rescore now pulls 4 contiguous lines per candidate
//   (16x less traffic).  Values are bit-copies and the sequential __fmaf_rn
//   chain order is unchanged -> exact pipeline intact (absmax 0 semantics
//   identical to R8, which passed; candidate counts deterministic on the
//   fixed seed-0 input, CAND_CAP 3072 unchanged).
//
// Exact pipeline: S = sequential __fmaf_rn chain c=0..63; normx = numpy
// pairwise(n=64); d = fl(normx - 2S); (d_bits<<13|k) u64 atomicMin =
// value-then-lowest-index; 4 k-quarters merge in vq_out.

#define DIM      64
#define NCODE    8192
#define NROWS    32768
#define RPB      128               // rows per block: 4 waves x 2 row-tiles x 16
#define KQ       2048              // codes per block (gridDim.y = 4)
#define CHUNK    128               // codes staged in LDS at a time (16 KB)
#define NCHUNK   (KQ / CHUNK)      // 16
#define SEED_CH  2                 // seed chunks (256 codes) for the threshold
#define HALF_DELTA 4.0e-5f
#define CAND_CAP 3072

typedef __attribute__((ext_vector_type(8))) short frag8;   // 8 bf16
typedef __attribute__((ext_vector_type(4))) float f32x4;

__device__ __forceinline__ unsigned short f2bf_rne(float f) {
  unsigned u = __float_as_uint(f);
  return (unsigned short)((u + 0x7FFFu + ((u >> 16) & 1u)) >> 16);
}

// ---- kernel 0a: x [32][64][1024] -> xT [32768][64] (bit-copy transpose) ----
__global__ __launch_bounds__(256) void xpose(const float* __restrict__ x,
                                             float* __restrict__ xT) {
  __shared__ float t[64][65];                  // +1 pad: conflict-free
  const int b = blockIdx.x >> 4, hw0 = (blockIdx.x & 15) << 6;
  const float* xb = x + (size_t)b * (DIM * 1024) + hw0;
  const int r = threadIdx.x & 63, c0 = threadIdx.x >> 6;   // 4 c's per pass
#pragma unroll
  for (int cc = 0; cc < DIM; cc += 4)
    t[r][cc + c0] = xb[(size_t)(cc + c0) * 1024 + r];      // coalesced reads
  __syncthreads();
  float* o = xT + (size_t)(b * 1024 + hw0) * DIM;
#pragma unroll
  for (int it = 0; it < 4; ++it) {
    const int idx = it * 256 + threadIdx.x;                // 0..1023
    const int row = idx >> 4, j = (idx & 15) << 2;
    float4 v = {t[row][j], t[row][j + 1], t[row][j + 2], t[row][j + 3]};
    *(float4*)(o + row * DIM + j) = v;                     // contiguous writes
  }
}

// ---- kernel 0b: codebook fp32 -> bf16 (RNE), 8192x64 = 1 MB in ws ----
__global__ __launch_bounds__(256) void cvt_emb(const float* __restrict__ emb,
                                               unsigned short* __restrict__ ebf) {
  const int i = (blockIdx.x * 256 + threadIdx.x) * 8;
  const float4 a = *(const float4*)(emb + i);
  const float4 c = *(const float4*)(emb + i + 4);
  union { unsigned short u[8]; uint4 v; } o;
  o.u[0] = f2bf_rne(a.x); o.u[1] = f2bf_rne(a.y);
  o.u[2] = f2bf_rne(a.z); o.u[3] = f2bf_rne(a.w);
  o.u[4] = f2bf_rne(c.x); o.u[5] = f2bf_rne(c.y);
  o.u[6] = f2bf_rne(c.z); o.u[7] = f2bf_rne(c.w);
  *(uint4*)(ebf + i) = o.v;
}

// ---- kernel 1: per (128-row group, 2048-code quarter) ----
__global__ __launch_bounds__(256) void vq_main(
    const float* __restrict__ x, const float* __restrict__ emb,
    const unsigned short* __restrict__ ebf, const float* __restrict__ xT,
    unsigned long long* __restrict__ wsbest)
{
  __shared__ uint4 ldsB[CHUNK * 8];            // 16 KB bf16 codes (16B units)
  __shared__ float s_normx[RPB];
  __shared__ float s_mrow[RPB];
  __shared__ unsigned long long s_best[RPB];
  __shared__ unsigned s_cand[CAND_CAP];        // (row_l<<11 | k_local)
  __shared__ int s_cnt;

  const int tid  = threadIdx.x;
  const int lane = tid & 63;
  const int wave = tid >> 6;
  const int s    = lane & 15;                  // MFMA m / n index
  const int q    = lane >> 4;                  // MFMA quad
  const int rowbase = blockIdx.x * RPB;
  const int kbase   = blockIdx.y * KQ;
  const int b    = rowbase >> 10;
  const int hw0  = rowbase & 1023;             // <= 896, block stays in one b
  const float* xb = x + (size_t)b * (DIM * 1024);

  if (tid == 0) s_cnt = 0;

  // normx for row rowbase+tid (tid<128) — numpy pairwise_sum(n=64), bit-exact
  if (tid < RPB) {
    s_best[tid] = ~0ull;
    float p[DIM];
#pragma unroll
    for (int c = 0; c < DIM; ++c) {
      const float v = xb[(size_t)c * 1024 + hw0 + tid];
      p[c] = __fmul_rn(v, v);
    }
    float r8[8];
#pragma unroll
    for (int j = 0; j < 8; ++j) {
      float ss = p[j];
#pragma unroll
      for (int m = 1; m < 8; ++m) ss = __fadd_rn(ss, p[m * 8 + j]);
      r8[j] = ss;
    }
    const float t0 = __fadd_rn(r8[0], r8[1]), t1 = __fadd_rn(r8[2], r8[3]);
    const float t2 = __fadd_rn(r8[4], r8[5]), t3 = __fadd_rn(r8[6], r8[7]);
    s_normx[tid] = __fadd_rn(__fadd_rn(t0, t1), __fadd_rn(t2, t3));
  }

  // A-frags: wave owns 32 rows = 2 row-tiles of 16.  A[m=s][k=q*8+j].
  frag8 afr[2][2];
#pragma unroll
  for (int rt = 0; rt < 2; ++rt) {
    const float* xp = xb + hw0 + wave * 32 + rt * 16 + s;
#pragma unroll
    for (int h = 0; h < 2; ++h) {
      frag8 f;
#pragma unroll
      for (int j = 0; j < 8; ++j)
        f[j] = (short)f2bf_rne(xp[(size_t)(h * 32 + q * 8 + j) * 1024]);
      afr[rt][h] = f;
    }
  }

  // LDS B layout: slot code*8 + (j ^ (code&7)) holds 16B chunk j of code.
  // Frag read (code = t*16+s): lbA -> chunk q (c 0..31), lbB -> chunk 4+q.
  const int lbA = s * 8 + ((q)     ^ (s & 7));
  const int lbB = s * 8 + ((4 + q) ^ (s & 7));
  const frag8* ldsF = (const frag8*)ldsB;

  // ---- sweep A (seed): per-row max of S~ over the first SEED_CH chunks ----
  f32x4 smax[2];
#pragma unroll
  for (int rt = 0; rt < 2; ++rt) smax[rt] = (f32x4){-1e30f, -1e30f, -1e30f, -1e30f};

  for (int ch = 0; ch < SEED_CH; ++ch) {
    __syncthreads();
    {
      const int code = tid >> 1, half = tid & 1;   // 2 threads per code, 64B each
      const uint4* src = (const uint4*)(ebf + (size_t)(kbase + ch * CHUNK + code) * DIM) + half * 4;
      const int sw = code & 7;
#pragma unroll
      for (int j = 0; j < 4; ++j) ldsB[code * 8 + ((half * 4 + j) ^ sw)] = src[j];
    }
    __syncthreads();
#pragma unroll
    for (int t = 0; t < 8; ++t) {
      const frag8 b0 = ldsF[lbA + t * 128];
      const frag8 b1 = ldsF[lbB + t * 128];
#pragma unroll
      for (int rt = 0; rt < 2; ++rt) {
        f32x4 d = {0.f, 0.f, 0.f, 0.f};
        d = __builtin_amdgcn_mfma_f32_16x16x32_bf16(afr[rt][0], b0, d, 0, 0, 0);
        d = __builtin_amdgcn_mfma_f32_16x16x32_bf16(afr[rt][1], b1, d, 0, 0, 0);
        smax[rt][0] = fmaxf(smax[rt][0], d[0]);
        smax[rt][1] = fmaxf(smax[rt][1], d[1]);
        smax[rt][2] = fmaxf(smax[rt][2], d[2]);
        smax[rt][3] = fmaxf(smax[rt][3], d[3]);
      }
    }
  }

  // reduce over the 16 code-columns (lane&15); D row = q*4+r
#pragma unroll
  for (int rt = 0; rt < 2; ++rt)
#pragma unroll
    for (int r = 0; r < 4; ++r) {
      float v = smax[rt][r];
      v = fmaxf(v, __shfl_xor(v, 1, 64));
      v = fmaxf(v, __shfl_xor(v, 2, 64));
      v = fmaxf(v, __shfl_xor(v, 4, 64));
      v = fmaxf(v, __shfl_xor(v, 8, 64));
      if (s == 0) s_mrow[wave * 32 + rt * 16 + q * 4 + r] = v;
    }
  __syncthreads();

  float thr[2][4];
#pragma unroll
  for (int rt = 0; rt < 2; ++rt)
#pragma unroll
    for (int r = 0; r < 4; ++r)
      thr[rt][r] = s_mrow[wave * 32 + rt * 16 + q * 4 + r] - HALF_DELTA;

  // ---- sweep B: full quarter, emit candidates vs seed threshold ----
  for (int ch = 0; ch < NCHUNK; ++ch) {
    __syncthreads();
    {
      const int code = tid >> 1, half = tid & 1;
      const uint4* src = (const uint4*)(ebf + (size_t)(kbase + ch * CHUNK + code) * DIM) + half * 4;
      const int sw = code & 7;
#pragma unroll
      for (int j = 0; j < 4; ++j) ldsB[code * 8 + ((half * 4 + j) ^ sw)] = src[j];
    }
    __syncthreads();
#pragma unroll
    for (int t = 0; t < 8; ++t) {
      const frag8 b0 = ldsF[lbA + t * 128];
      const frag8 b1 = ldsF[lbB + t * 128];
      const int kl = ch * CHUNK + t * 16 + s;
#pragma unroll
      for (int rt = 0; rt < 2; ++rt) {
        f32x4 d = {0.f, 0.f, 0.f, 0.f};
        d = __builtin_amdgcn_mfma_f32_16x16x32_bf16(afr[rt][0], b0, d, 0, 0, 0);
        d = __builtin_amdgcn_mfma_f32_16x16x32_bf16(afr[rt][1], b1, d, 0, 0, 0);
#pragma unroll
        for (int r = 0; r < 4; ++r) {
          if (d[r] >= thr[rt][r]) {
            const int pos = atomicAdd(&s_cnt, 1);
            if (pos < CAND_CAP)
              s_cand[pos] = ((unsigned)(wave * 32 + rt * 16 + q * 4 + r) << 11) | (unsigned)kl;
          }
        }
      }
    }
  }
  __syncthreads();

  // ---- exact rescore of candidates (bit-exact numpy fp32 pipeline) ----
  // xT read: row-major, 4 contiguous lines per candidate (vs 64 strided).
  const int cnt = min(s_cnt, CAND_CAP);
  for (int i = tid; i < cnt; i += 256) {
    const unsigned e = s_cand[i];
    const int row_l = (int)(e >> 11);
    const int kg = kbase + (int)(e & 0x7FFu);
    const float* ep = emb + (size_t)kg * DIM;
    const float* xp = xT + (size_t)(rowbase + row_l) * DIM;
    float S = 0.f;
#pragma unroll
    for (int c = 0; c < DIM; ++c) S = __fmaf_rn(xp[c], ep[c], S);
    const float dd = __fsub_rn(s_normx[row_l], __fadd_rn(S, S));
    const unsigned long long pack =
        ((unsigned long long)__float_as_uint(dd) << 13) | (unsigned long long)kg;
    atomicMin(&s_best[row_l], pack);
  }
  __syncthreads();

  if (tid < RPB)
    wsbest[(size_t)(rowbase + tid) * 4 + blockIdx.y] = s_best[tid];
}

// ---- kernel 2: merge quarters, write indices + gather z_q ----
__global__ __launch_bounds__(256) void vq_out(
    const float* __restrict__ emb, const unsigned long long* __restrict__ wsbest,
    float* __restrict__ zq, float* __restrict__ idx_out)
{
  const int row = blockIdx.x * 256 + threadIdx.x;
  unsigned long long p = wsbest[(size_t)row * 4];
#pragma unroll
  for (int j = 1; j < 4; ++j) {
    const unsigned long long pj = wsbest[(size_t)row * 4 + j];
    if (pj < p) p = pj;                        // d-major, then lowest k
  }
  const int k = (int)(p & 0x1FFFull);
  idx_out[row] = (float)k;
  const int b = row >> 10, hw = row & 1023;
  const float* ep = emb + (size_t)k * DIM;
  float* zp = zq + (size_t)b * (DIM * 1024) + hw;
#pragma unroll
  for (int c = 0; c < DIM; ++c) zp[(size_t)c * 1024] = ep[c];
}

extern "C" void kernel_launch(void* const* d_in, const int* in_sizes, int n_in,
                              void* d_out, int out_size, void* d_ws, size_t ws_size,
                              hipStream_t stream) {
  const float* x   = (const float*)d_in[0];   // [32, 64, 32, 32] fp32
  const float* emb = (const float*)d_in[1];   // [8192, 64] fp32

  float* zq      = (float*)d_out;
  float* idx_out = zq + (size_t)NROWS * DIM;

  unsigned short*     ebf    = (unsigned short*)d_ws;                          // 1 MB
  unsigned long long* wsbest = (unsigned long long*)((char*)d_ws + (1 << 20)); // 1 MB

  // xT (8 MB) borrows the zq output region; vq_out fully overwrites it later
  // and never reads zq, so this is stream-order safe with zero ws growth.
  float* xT = zq;

  xpose<<<dim3(512), 256, 0, stream>>>(x, xT);
  cvt_emb<<<dim3(256), 256, 0, stream>>>(emb, ebf);
  vq_main<<<dim3(NROWS / RPB, 4), 256, 0, stream>>>(x, emb, ebf, xT, wsbest);
  vq_out<<<dim3(NROWS / 256), 256, 0, stream>>>(emb, wsbest, zq, idx_out);
}

// Round 6
// 206.014 us; speedup vs baseline: 1.6386x; 1.4157x over previous
//
#include <hip/hip_runtime.h>
#include <math.h>

// VectorQuantizer, MFMA filter + exact-fp32 rescore.  N=32768 rows x K=8192
// codes, dim 64.
//
// R10b = R10 resubmitted verbatim (previous run died to an infra error:
// "MI355X container failed twice" — no kernel result).  Audit found no
// hang/OOB risk: barriers are at uniform loop-tops, ballot branch is
// wave-uniform, s_candw write is capped, LDS ~30KB.
//
// R10 = R9 with the candidate path rebuilt (the measured poison).
//   Cycle accounting across R5/R6/R9 isolates ~100 CU-cycles PER CANDIDATE
//   (R5: 140 cands/block -> 57k cyc; R8/R9: 1024 -> ~400k cyc) while phase
//   cost stayed ~7k.  SQ_LDS_BANK_CONFLICT scaled exactly 8x with candidate
//   count (31k -> 248k) -> the cost is the emission/rescore path: the
//   atomicAdd(&s_cnt) RETURN atomic (ds_add_rtn, ~120cyc lgkmcnt stall mid
//   MFMA loop) + shared-list traffic.  Fix:
//   1. ballot-compaction emission: __ballot -> wave-uniform branch -> mbcnt
//      offset -> fire-and-forget ds_write into a PER-WAVE region, counter in
//      SGPR.  Zero LDS atomics, zero return latency in the sweep.
//   2. per-wave rescore: each wave rescores its own region (it owns rows
//      wave*32..+31); s_best atomicMin moves off the hot loop.
//   3. #pragma unroll 1 on the seed loop (R8's trip-2 full unroll bloated
//      VGPR 60->120); s_mrow and s_cnt deleted (butterfly already leaves
//      every lane its row max: row q*4+r is s-independent).
//   Exact rescore math, thresholds, xT, and encodings unchanged (absmax 0
//   semantics identical to R9).  CAP_W=768/wave (expected ~256, >20 sigma).
//
// Exact pipeline: S = sequential __fmaf_rn chain c=0..63; normx = numpy
// pairwise(n=64); d = fl(normx - 2S); (d_bits<<13|k) u64 atomicMin =
// value-then-lowest-index; 4 k-quarters merge in vq_out.

#define DIM      64
#define NCODE    8192
#define NROWS    32768
#define RPB      128               // rows per block: 4 waves x 2 row-tiles x 16
#define KQ       2048              // codes per block (gridDim.y = 4)
#define CHUNK    128               // codes staged in LDS at a time (16 KB)
#define NCHUNK   (KQ / CHUNK)      // 16
#define SEED_CH  2                 // seed chunks (256 codes) for the threshold
#define HALF_DELTA 4.0e-5f
#define CAP_W    768               // per-wave candidate cap

typedef __attribute__((ext_vector_type(8))) short frag8;   // 8 bf16
typedef __attribute__((ext_vector_type(4))) float f32x4;

__device__ __forceinline__ unsigned short f2bf_rne(float f) {
  unsigned u = __float_as_uint(f);
  return (unsigned short)((u + 0x7FFFu + ((u >> 16) & 1u)) >> 16);
}

// ---- kernel 0a: x [32][64][1024] -> xT [32768][64] (bit-copy transpose) ----
__global__ __launch_bounds__(256) void xpose(const float* __restrict__ x,
                                             float* __restrict__ xT) {
  __shared__ float t[64][65];                  // +1 pad: conflict-free
  const int b = blockIdx.x >> 4, hw0 = (blockIdx.x & 15) << 6;
  const float* xb = x + (size_t)b * (DIM * 1024) + hw0;
  const int r = threadIdx.x & 63, c0 = threadIdx.x >> 6;   // 4 c's per pass
#pragma unroll
  for (int cc = 0; cc < DIM; cc += 4)
    t[r][cc + c0] = xb[(size_t)(cc + c0) * 1024 + r];      // coalesced reads
  __syncthreads();
  float* o = xT + (size_t)(b * 1024 + hw0) * DIM;
#pragma unroll
  for (int it = 0; it < 4; ++it) {
    const int idx = it * 256 + threadIdx.x;                // 0..1023
    const int row = idx >> 4, j = (idx & 15) << 2;
    float4 v = {t[row][j], t[row][j + 1], t[row][j + 2], t[row][j + 3]};
    *(float4*)(o + row * DIM + j) = v;                     // contiguous writes
  }
}

// ---- kernel 0b: codebook fp32 -> bf16 (RNE), 8192x64 = 1 MB in ws ----
__global__ __launch_bounds__(256) void cvt_emb(const float* __restrict__ emb,
                                               unsigned short* __restrict__ ebf) {
  const int i = (blockIdx.x * 256 + threadIdx.x) * 8;
  const float4 a = *(const float4*)(emb + i);
  const float4 c = *(const float4*)(emb + i + 4);
  union { unsigned short u[8]; uint4 v; } o;
  o.u[0] = f2bf_rne(a.x); o.u[1] = f2bf_rne(a.y);
  o.u[2] = f2bf_rne(a.z); o.u[3] = f2bf_rne(a.w);
  o.u[4] = f2bf_rne(c.x); o.u[5] = f2bf_rne(c.y);
  o.u[6] = f2bf_rne(c.z); o.u[7] = f2bf_rne(c.w);
  *(uint4*)(ebf + i) = o.v;
}

// ---- kernel 1: per (128-row group, 2048-code quarter) ----
__global__ __launch_bounds__(256) void vq_main(
    const float* __restrict__ x, const float* __restrict__ emb,
    const unsigned short* __restrict__ ebf, const float* __restrict__ xT,
    unsigned long long* __restrict__ wsbest)
{
  __shared__ uint4 ldsB[CHUNK * 8];            // 16 KB bf16 codes (16B units)
  __shared__ float s_normx[RPB];
  __shared__ unsigned long long s_best[RPB];
  __shared__ unsigned s_candw[4][CAP_W];       // per-wave: (row_in_wave<<11|kl)

  const int tid  = threadIdx.x;
  const int lane = tid & 63;
  const int wave = tid >> 6;
  const int s    = lane & 15;                  // MFMA m / n index
  const int q    = lane >> 4;                  // MFMA quad
  const int rowbase = blockIdx.x * RPB;
  const int kbase   = blockIdx.y * KQ;
  const int b    = rowbase >> 10;
  const int hw0  = rowbase & 1023;             // <= 896, block stays in one b
  const float* xb = x + (size_t)b * (DIM * 1024);

  // normx for row rowbase+tid (tid<128) — numpy pairwise_sum(n=64), bit-exact
  if (tid < RPB) {
    s_best[tid] = ~0ull;
    float p[DIM];
#pragma unroll
    for (int c = 0; c < DIM; ++c) {
      const float v = xb[(size_t)c * 1024 + hw0 + tid];
      p[c] = __fmul_rn(v, v);
    }
    float r8[8];
#pragma unroll
    for (int j = 0; j < 8; ++j) {
      float ss = p[j];
#pragma unroll
      for (int m = 1; m < 8; ++m) ss = __fadd_rn(ss, p[m * 8 + j]);
      r8[j] = ss;
    }
    const float t0 = __fadd_rn(r8[0], r8[1]), t1 = __fadd_rn(r8[2], r8[3]);
    const float t2 = __fadd_rn(r8[4], r8[5]), t3 = __fadd_rn(r8[6], r8[7]);
    s_normx[tid] = __fadd_rn(__fadd_rn(t0, t1), __fadd_rn(t2, t3));
  }

  // A-frags: wave owns 32 rows = 2 row-tiles of 16.  A[m=s][k=q*8+j].
  frag8 afr[2][2];
#pragma unroll
  for (int rt = 0; rt < 2; ++rt) {
    const float* xp = xb + hw0 + wave * 32 + rt * 16 + s;
#pragma unroll
    for (int h = 0; h < 2; ++h) {
      frag8 f;
#pragma unroll
      for (int j = 0; j < 8; ++j)
        f[j] = (short)f2bf_rne(xp[(size_t)(h * 32 + q * 8 + j) * 1024]);
      afr[rt][h] = f;
    }
  }

  // LDS B layout: slot code*8 + (j ^ (code&7)) holds 16B chunk j of code.
  // Frag read (code = t*16+s): lbA -> chunk q (c 0..31), lbB -> chunk 4+q.
  const int lbA = s * 8 + ((q)     ^ (s & 7));
  const int lbB = s * 8 + ((4 + q) ^ (s & 7));
  const frag8* ldsF = (const frag8*)ldsB;

  // ---- sweep A (seed): per-row max of S~ over the first SEED_CH chunks ----
  f32x4 smax[2];
#pragma unroll
  for (int rt = 0; rt < 2; ++rt) smax[rt] = (f32x4){-1e30f, -1e30f, -1e30f, -1e30f};

#pragma unroll 1
  for (int ch = 0; ch < SEED_CH; ++ch) {
    __syncthreads();
    {
      const int code = tid >> 1, half = tid & 1;   // 2 threads per code, 64B each
      const uint4* src = (const uint4*)(ebf + (size_t)(kbase + ch * CHUNK + code) * DIM) + half * 4;
      const int sw = code & 7;
#pragma unroll
      for (int j = 0; j < 4; ++j) ldsB[code * 8 + ((half * 4 + j) ^ sw)] = src[j];
    }
    __syncthreads();
#pragma unroll
    for (int t = 0; t < 8; ++t) {
      const frag8 b0 = ldsF[lbA + t * 128];
      const frag8 b1 = ldsF[lbB + t * 128];
#pragma unroll
      for (int rt = 0; rt < 2; ++rt) {
        f32x4 d = {0.f, 0.f, 0.f, 0.f};
        d = __builtin_amdgcn_mfma_f32_16x16x32_bf16(afr[rt][0], b0, d, 0, 0, 0);
        d = __builtin_amdgcn_mfma_f32_16x16x32_bf16(afr[rt][1], b1, d, 0, 0, 0);
        smax[rt][0] = fmaxf(smax[rt][0], d[0]);
        smax[rt][1] = fmaxf(smax[rt][1], d[1]);
        smax[rt][2] = fmaxf(smax[rt][2], d[2]);
        smax[rt][3] = fmaxf(smax[rt][3], d[3]);
      }
    }
  }

  // butterfly over the 16 code-columns: row q*4+r is s-independent, so after
  // xor{1,2,4,8} EVERY lane holds its row's seed max — no LDS round trip.
  float thr[2][4];
#pragma unroll
  for (int rt = 0; rt < 2; ++rt)
#pragma unroll
    for (int r = 0; r < 4; ++r) {
      float v = smax[rt][r];
      v = fmaxf(v, __shfl_xor(v, 1, 64));
      v = fmaxf(v, __shfl_xor(v, 2, 64));
      v = fmaxf(v, __shfl_xor(v, 4, 64));
      v = fmaxf(v, __shfl_xor(v, 8, 64));
      thr[rt][r] = v - HALF_DELTA;
    }

  // ---- sweep B: full quarter, ballot-compaction emission (no atomics) ----
  int wcnt = 0;                                // wave-uniform (SGPR)
  for (int ch = 0; ch < NCHUNK; ++ch) {
    __syncthreads();
    {
      const int code = tid >> 1, half = tid & 1;
      const uint4* src = (const uint4*)(ebf + (size_t)(kbase + ch * CHUNK + code) * DIM) + half * 4;
      const int sw = code & 7;
#pragma unroll
      for (int j = 0; j < 4; ++j) ldsB[code * 8 + ((half * 4 + j) ^ sw)] = src[j];
    }
    __syncthreads();
#pragma unroll
    for (int t = 0; t < 8; ++t) {
      const frag8 b0 = ldsF[lbA + t * 128];
      const frag8 b1 = ldsF[lbB + t * 128];
      const int kl = ch * CHUNK + t * 16 + s;
#pragma unroll
      for (int rt = 0; rt < 2; ++rt) {
        f32x4 d = {0.f, 0.f, 0.f, 0.f};
        d = __builtin_amdgcn_mfma_f32_16x16x32_bf16(afr[rt][0], b0, d, 0, 0, 0);
        d = __builtin_amdgcn_mfma_f32_16x16x32_bf16(afr[rt][1], b1, d, 0, 0, 0);
#pragma unroll
        for (int r = 0; r < 4; ++r) {
          const bool pr = d[r] >= thr[rt][r];
          const unsigned long long m = __ballot(pr);
          if (m) {                             // wave-uniform branch
            const int off = __builtin_amdgcn_mbcnt_hi(
                (unsigned)(m >> 32),
                __builtin_amdgcn_mbcnt_lo((unsigned)m, 0u));
            if (pr) {
              const int pos = wcnt + off;
              if (pos < CAP_W)
                s_candw[wave][pos] =
                    ((unsigned)(rt * 16 + q * 4 + r) << 11) | (unsigned)kl;
            }
            wcnt += __builtin_popcountll(m);
          }
        }
      }
    }
  }

  // ---- exact rescore: each wave rescores its own candidates ----
  const int wc = min(wcnt, CAP_W);
  for (int i = lane; i < wc; i += 64) {
    const unsigned e = s_candw[wave][i];
    const int row_l = wave * 32 + (int)(e >> 11);
    const int kg = kbase + (int)(e & 0x7FFu);
    const float* ep = emb + (size_t)kg * DIM;
    const float* xp = xT + (size_t)(rowbase + row_l) * DIM;
    float S = 0.f;
#pragma unroll
    for (int c = 0; c < DIM; ++c) S = __fmaf_rn(xp[c], ep[c], S);
    const float dd = __fsub_rn(s_normx[row_l], __fadd_rn(S, S));
    const unsigned long long pack =
        ((unsigned long long)__float_as_uint(dd) << 13) | (unsigned long long)kg;
    atomicMin(&s_best[row_l], pack);
  }
  __syncthreads();

  if (tid < RPB)
    wsbest[(size_t)(rowbase + tid) * 4 + blockIdx.y] = s_best[tid];
}

// ---- kernel 2: merge quarters, write indices + gather z_q ----
__global__ __launch_bounds__(256) void vq_out(
    const float* __restrict__ emb, const unsigned long long* __restrict__ wsbest,
    float* __restrict__ zq, float* __restrict__ idx_out)
{
  const int row = blockIdx.x * 256 + threadIdx.x;
  unsigned long long p = wsbest[(size_t)row * 4];
#pragma unroll
  for (int j = 1; j < 4; ++j) {
    const unsigned long long pj = wsbest[(size_t)row * 4 + j];
    if (pj < p) p = pj;                        // d-major, then lowest k
  }
  const int k = (int)(p & 0x1FFFull);
  idx_out[row] = (float)k;
  const int b = row >> 10, hw = row & 1023;
  const float* ep = emb + (size_t)k * DIM;
  float* zp = zq + (size_t)b * (DIM * 1024) + hw;
#pragma unroll
  for (int c = 0; c < DIM; ++c) zp[(size_t)c * 1024] = ep[c];
}

extern "C" void kernel_launch(void* const* d_in, const int* in_sizes, int n_in,
                              void* d_out, int out_size, void* d_ws, size_t ws_size,
                              hipStream_t stream) {
  const float* x   = (const float*)d_in[0];   // [32, 64, 32, 32] fp32
  const float* emb = (const float*)d_in[1];   // [8192, 64] fp32

  float* zq      = (float*)d_out;
  float* idx_out = zq + (size_t)NROWS * DIM;

  unsigned short*     ebf    = (unsigned short*)d_ws;                          // 1 MB
  unsigned long long* wsbest = (unsigned long long*)((char*)d_ws + (1 << 20)); // 1 MB

  // xT (8 MB) borrows the zq output region; vq_out fully overwrites it later
  // and never reads zq, so this is stream-order safe with zero ws growth.
  float* xT = zq;

  xpose<<<dim3(512), 256, 0, stream>>>(x, xT);
  cvt_emb<<<dim3(256), 256, 0, stream>>>(emb, ebf);
  vq_main<<<dim3(NROWS / RPB, 4), 256, 0, stream>>>(x, emb, ebf, xT, wsbest);
  vq_out<<<dim3(NROWS / 256), 256, 0, stream>>>(emb, wsbest, zq, idx_out);
}